// Round 1
// baseline (44.807 us; speedup 1.0000x reference)
//
#include <hip/hip_runtime.h>

// CumulativeFlattenedLinear: per-64-timestep-window per-timestep projection
// (C=16 -> O=16, per-s weight slice, first 16 slots zero) + causal cumsum + bias.
//
// Structure: lane = s (0..63). Each wave owns GW=8 consecutive windows of one b.
// - x loads: lane s reads x[b,c,g*64+s] -> consecutive addresses across lanes (coalesced 256B).
// - weights: staged once per block into LDS as wl[o][c][s] (lane stride 1 -> conflict-free).
// - cumsum: 64-lane inclusive scan via DPP (row_shr 1/2/4/8 + row_bcast15/31), pure VALU.
// - stores: out[b,o,g*64+s] coalesced across lanes.
// HBM ideal = 128 MiB -> ~20us floor.

#define BB 8
#define CC 16
#define TT 131072
#define OO 16
#define NK 48
#define ND 16
#define SS 64
#define GG (TT / SS)      // 2048 windows per (b,c) row
#define GW 8              // windows per wave
#define NWAVES 4          // waves per block
#define GB (GW * NWAVES)  // 32 windows per block

// 64-lane inclusive prefix sum, DPP-based (no LDS traffic).
#define SCAN_STEP(CTRL, RMASK)                                                   \
  {                                                                              \
    int t_ = __builtin_amdgcn_update_dpp(0, __float_as_int(v), (CTRL), (RMASK),  \
                                         0xf, true);                             \
    v += __int_as_float(t_);                                                     \
  }

__device__ __forceinline__ float wave_scan64(float v) {
  SCAN_STEP(0x111, 0xf)  // row_shr:1
  SCAN_STEP(0x112, 0xf)  // row_shr:2
  SCAN_STEP(0x114, 0xf)  // row_shr:4
  SCAN_STEP(0x118, 0xf)  // row_shr:8  -> inclusive scan within each 16-lane row
  SCAN_STEP(0x142, 0xa)  // row_bcast15 -> rows 1,3 get prev-row total
  SCAN_STEP(0x143, 0xc)  // row_bcast31 -> rows 2,3 get rows0+1 total
  return v;
}

__global__ __launch_bounds__(256, 2) void cfl_kernel(
    const float* __restrict__ x, const float* __restrict__ weight,
    const float* __restrict__ bias, float* __restrict__ out) {
  __shared__ float wl[OO * CC * SS];  // [o][c][s], 64 KiB

  const int tid = threadIdx.x;

  // Build the per-timestep weight table: wl[o][c][s] = weight[o, c*48 + (s-16)], 0 for s<16.
  for (int i = 0; i < (OO * CC * SS) / 256; ++i) {
    int idx = i * 256 + tid;
    int o = idx >> 10;          // / (C*S) = 1024
    int c = (idx >> 6) & 15;
    int s = idx & 63;
    float v = 0.f;
    if (s >= ND) v = weight[o * (CC * NK) + c * NK + (s - ND)];
    wl[idx] = v;
  }
  __syncthreads();

  const int lane = tid & 63;
  const int wid = tid >> 6;
  const int n0 = blockIdx.x * GB + wid * GW;  // first linear window (b*G + g)
  const int b = n0 / GG;                       // block never straddles b (2048 % 32 == 0)
  const int g0 = n0 % GG;

  // Cache this wave's x slab in registers: xv[k][c] = x[b, c, (g0+k)*64 + lane]
  const float* xb = x + (size_t)b * CC * TT + g0 * SS + lane;
  float xv[GW][CC];
#pragma unroll
  for (int k = 0; k < GW; ++k)
#pragma unroll
    for (int c = 0; c < CC; ++c)
      xv[k][c] = xb[c * TT + k * SS];

  float* ob = out + (size_t)b * OO * TT + g0 * SS + lane;
  for (int o = 0; o < OO; ++o) {
    float w[CC];
#pragma unroll
    for (int c = 0; c < CC; ++c)
      w[c] = wl[(o * CC + c) * SS + lane];
    const float bo = bias[o];
#pragma unroll
    for (int k = 0; k < GW; ++k) {
      float p = 0.f;
#pragma unroll
      for (int c = 0; c < CC; ++c)
        p = fmaf(xv[k][c], w[c], p);
      float cs = wave_scan64(p);
      ob[o * TT + k * SS] = cs + bo;
    }
  }
}

extern "C" void kernel_launch(void* const* d_in, const int* in_sizes, int n_in,
                              void* d_out, int out_size, void* d_ws, size_t ws_size,
                              hipStream_t stream) {
  const float* x = (const float*)d_in[0];
  const float* weight = (const float*)d_in[1];
  const float* bias = (const float*)d_in[2];
  float* out = (float*)d_out;

  // B*G window-slots = 16384; 32 per block -> 512 blocks (2 per CU, 64 KiB LDS each).
  cfl_kernel<<<512, 256, 0, stream>>>(x, weight, bias, out);
}